// Round 11
// baseline (2657.483 us; speedup 1.0000x reference)
//
#include <hip/hip_runtime.h>
#include <hip/hip_bf16.h>

#define NN 768
#define CSD 384
#define CZD 128
#define HD 12
#define DOUT 2112
#define II 2

#define SCALE_SINGLE 0.25f
#define SCALE_FRAME (-0.11785113019775793f)   /* -1/sqrt(72) */

__device__ __forceinline__ float dot4f(float4 a, float4 b){
    return fmaf(a.x,b.x, fmaf(a.y,b.y, fmaf(a.z,b.z, a.w*b.w)));
}
__device__ __forceinline__ unsigned f2bf(float f){   // fp32 -> bf16 bits (RNE)
    unsigned u = __float_as_uint(f);
    return (u + 0x7fffu + ((u >> 16) & 1u)) >> 16;
}
__device__ __forceinline__ float bf_lo(unsigned u){ return __uint_as_float(u << 16); }
__device__ __forceinline__ float bf_hi(unsigned u){ return __uint_as_float(u & 0xffff0000u); }

// ---------------- K1: projections + frame apply, II=2 residues per block ----------------
__global__ __launch_bounds__(384) void k_proj(
    const float* __restrict__ s, const float* __restrict__ R, const float* __restrict__ tv,
    const float* __restrict__ Wq, const float* __restrict__ Wk, const float* __restrict__ Wv,
    const float* __restrict__ Wqp, const float* __restrict__ Wkp, const float* __restrict__ Wvp,
    float* __restrict__ q, float* __restrict__ k, float* __restrict__ v,
    float* __restrict__ gq, float* __restrict__ gk, float* __restrict__ gv,
    float* __restrict__ sqq, float* __restrict__ sqk)
{
    __shared__ float s_l[II*CSD];
    __shared__ float praw[II][576];
    __shared__ float sq_pt[II][96];
    int i0 = blockIdx.x * II, t = threadIdx.x;
    if (t < II*CSD/4){
        const float4* s4 = (const float4*)(s + (size_t)i0*CSD);
        ((float4*)s_l)[t] = s4[t];
    }
    __syncthreads();

    int cols[3] = {t, t+384, t+768};
    const float* Wp[3]; int st[3], lc[3];
    #pragma unroll
    for (int m=0;m<3;m++){
        int c = cols[m];
        if (c < 192){ Wp[m]=Wq;  st[m]=192; lc[m]=c; }
        else if (c < 384){ Wp[m]=Wk;  st[m]=192; lc[m]=c-192; }
        else if (c < 576){ Wp[m]=Wv;  st[m]=192; lc[m]=c-384; }
        else if (c < 720){ Wp[m]=Wqp; st[m]=144; lc[m]=c-576; }
        else if (c < 864){ Wp[m]=Wkp; st[m]=144; lc[m]=c-720; }
        else { Wp[m]=Wvp; st[m]=288; lc[m]=c-864; }
    }
    float acc[3][II];
    #pragma unroll
    for (int m=0;m<3;m++)
        #pragma unroll
        for (int ii=0;ii<II;ii++) acc[m][ii]=0.f;

    #pragma unroll 4
    for (int r=0;r<CSD;r++){
        float w0 = Wp[0][(size_t)r*st[0]+lc[0]];
        float w1 = Wp[1][(size_t)r*st[1]+lc[1]];
        float w2 = Wp[2][(size_t)r*st[2]+lc[2]];
        #pragma unroll
        for (int ii=0;ii<II;ii++){
            float sv = s_l[ii*CSD + r];
            acc[0][ii] = fmaf(sv, w0, acc[0][ii]);
            acc[1][ii] = fmaf(sv, w1, acc[1][ii]);
            acc[2][ii] = fmaf(sv, w2, acc[2][ii]);
        }
    }
    #pragma unroll
    for (int m=0;m<3;m++){
        int c = cols[m];
        #pragma unroll
        for (int ii=0;ii<II;ii++){
            float val = acc[m][ii];
            size_t i = i0 + ii;
            if (c < 192) q[i*192 + c] = val;
            else if (c < 384) k[i*192 + (c-192)] = val;
            else if (c < 576) v[i*192 + (c-384)] = val;
            else praw[ii][c-576] = val;
        }
    }
    __syncthreads();

    if (t < 192){
        #pragma unroll
        for (int ii=0;ii<II;ii++){
            size_t i = i0 + ii;
            const float* Ri = R + i*9;
            float R00=Ri[0],R01=Ri[1],R02=Ri[2];
            float R10=Ri[3],R11=Ri[4],R12=Ri[5];
            float R20=Ri[6],R21=Ri[7],R22=Ri[8];
            float t0=tv[i*3+0],t1=tv[i*3+1],t2=tv[i*3+2];
            int src; float* dst; int sqslot=-1;
            if (t < 48){ src = t*3; dst = gq + i*144 + t*3; sqslot = t; }
            else if (t < 96){ int u=t-48; src = 144+u*3; dst = gk + i*144 + u*3; sqslot = 48+u; }
            else { int u=t-96; src = 288+u*3; dst = gv + i*288 + u*3; }
            float x=praw[ii][src], y=praw[ii][src+1], zc=praw[ii][src+2];
            float g0 = fmaf(R00,x, fmaf(R01,y, fmaf(R02,zc, t0)));
            float g1 = fmaf(R10,x, fmaf(R11,y, fmaf(R12,zc, t1)));
            float g2 = fmaf(R20,x, fmaf(R21,y, fmaf(R22,zc, t2)));
            dst[0]=g0; dst[1]=g1; dst[2]=g2;
            if (sqslot >= 0) sq_pt[ii][sqslot] = g0*g0 + g1*g1 + g2*g2;
        }
    }
    __syncthreads();
    if (t < II*HD){
        int ii = t / HD, h = t % HD;
        float s1 = sq_pt[ii][h*4]+sq_pt[ii][h*4+1]+sq_pt[ii][h*4+2]+sq_pt[ii][h*4+3];
        float s2 = sq_pt[ii][48+h*4]+sq_pt[ii][48+h*4+1]+sq_pt[ii][48+h*4+2]+sq_pt[ii][48+h*4+3];
        sqq[(size_t)(i0+ii)*HD + h] = s1;
        sqk[(size_t)(i0+ii)*HD + h] = s2;
    }
}

// ---------------- K2: fused IPA single-pass, Wb-in-regs, 2 blocks/CU ----------------
// 512 threads = 8 waves, ~40KB LDS, VGPR capped 128 -> 2 blocks/CU.
// R10's proven 2-barrier online-softmax skeleton. Roles:
//  waves 0-5 (pair+o_z): phase1 lane=(j=lane&31, chalf=lane>>5), heads {2w,2w+1};
//    z half-row (16 b128), Wb packed-bf16 in 64 VGPRs; chalf-combine via shfl_xor(32).
//    phase2 lane=(c4=lane&31, jhalf=lane>>5): 16 z reads + broadcast w; jhalf-combine at end.
//  waves 6-7: single+frame (qloc in LDS) one tile ahead -> SFl; o_s/so in phase2.
__global__ __launch_bounds__(512, 4) void k_ipa(
    const float* __restrict__ z, const float* __restrict__ Wb, const float* __restrict__ scale_head,
    const float* __restrict__ q, const float* __restrict__ k,
    const float* __restrict__ gq, const float* __restrict__ gk,
    const float* __restrict__ sqq, const float* __restrict__ sqk,
    const float* __restrict__ v, const float* __restrict__ gv,
    const float* __restrict__ R, const float* __restrict__ tv,
    float* __restrict__ att)
{
    __shared__ float ztile[2][32][CZD];   // 32KB dbuf
    __shared__ float SFl[2][HD][32];      // single+frame, 1 tile ahead
    __shared__ float w_l[HD][32];
    __shared__ float scale_l[HD];
    __shared__ float s_l[HD];
    __shared__ float so_l[288];
    __shared__ float qloc[360];           // q(192) gq(144) sqq(12) sp(12)

    int i = blockIdx.x, t = threadIdx.x;
    int wave = t >> 6, lane = t & 63;
    int jl = lane & 31, chalf = lane >> 5;
    int h0 = wave*2;                                   // pair waves 0-5
    int rS = lane & 31, gS = (wave-6)*2 + (lane>>5);   // SF waves 6-7

    if (t < 192) qloc[t] = q[(size_t)i*192 + t];
    else if (t < 336) qloc[t] = gq[(size_t)i*144 + (t-192)];
    else if (t < 348) qloc[t] = sqq[(size_t)i*HD + (t-336)];
    else if (t < 360){
        int h = t-348;
        float shv = scale_head[h];
        float sp = (shv > 20.f) ? shv : log1pf(__expf(shv));
        qloc[t] = SCALE_FRAME * sp;
    }

    const char* zi = (const char*)(z + (size_t)i*NN*CZD);
    float* zbase = &ztile[0][0][0];

#define STAGE(JT, BUF) do { \
    const char* _zb = zi + (size_t)(JT)*16384; \
    char* _lb = (char*)zbase + (size_t)(BUF)*16384; \
    _Pragma("unroll") \
    for (int _m=0;_m<2;_m++){ \
        int _d = t*16 + _m*8192; \
        int _j = _d >> 9; \
        int _b = _d & 511; \
        int _sb = _b ^ ((_j & 31) << 4); \
        __builtin_amdgcn_global_load_lds((const __attribute__((address_space(1))) void*)(_zb + (size_t)_j*512 + _sb), \
            (__attribute__((address_space(3))) void*)(_lb + _d), 16, 0, 0); \
    } \
  } while(0)

    // pair waves: Wb packed bf16, 2 heads x 64 c (this lane's c-half) -> 64 VGPRs
    unsigned wbA[32], wbB[32];
    if (wave < 6){
        #pragma unroll
        for (int cc=0; cc<32; ++cc){
            int c0 = (chalf<<6) + cc*2;
            const float* p0 = Wb + (size_t)c0*HD + h0;
            const float* p1 = p0 + HD;
            float a0 = p0[0], b0 = p0[1];
            float a1 = p1[0], b1 = p1[1];
            wbA[cc] = f2bf(a0) | (f2bf(a1) << 16);
            wbB[cc] = f2bf(b0) | (f2bf(b1) << 16);
        }
    }

    const float4* gsrc = nullptr; int gstride = 0; int hso = 0;
    if (wave >= 6){
        if (t >= 384 && t < 432){ int u=t-384; hso = u>>2; gsrc = (const float4*)v  + hso*4 + (u&3); gstride = 48; }
        else if (t >= 432 && t < 504){ int u=t-432; hso = u/6;  gsrc = (const float4*)gv + hso*6 + (u%6); gstride = 72; }
    }

    STAGE(0, 0);
    __syncthreads();   // qloc published; STAGE(0) drained

    const float4* qv4 = (const float4*)qloc;
    const float4* gq4 = (const float4*)(qloc + 192);

    // prologue: SF(0)
    if (wave >= 6){
        int jg = rS;
        const float4* kp  = (const float4*)(k  + (size_t)jg*192);
        const float4* gkp = (const float4*)(gk + (size_t)jg*144);
        #pragma unroll
        for (int hs=0; hs<3; ++hs){
            int hq = gS*3 + hs;
            float sng = dot4f(qv4[hq*4+0], kp[hq*4+0]) + dot4f(qv4[hq*4+1], kp[hq*4+1])
                      + dot4f(qv4[hq*4+2], kp[hq*4+2]) + dot4f(qv4[hq*4+3], kp[hq*4+3]);
            float fdot = dot4f(gq4[hq*3+0], gkp[hq*3+0]) + dot4f(gq4[hq*3+1], gkp[hq*3+1])
                       + dot4f(gq4[hq*3+2], gkp[hq*3+2]);
            float d2 = qloc[336+hq] + sqk[(size_t)jg*HD + hq] - 2.0f*fdot;
            SFl[0][hq][rS] = fmaf(SCALE_SINGLE, sng, qloc[348+hq]*d2);
        }
    }

    float m_runA = -1e30f, s_runA = 0.f, m_runB = -1e30f, s_runB = 0.f;
    float4 azA = {0,0,0,0}, azB = {0,0,0,0};
    float4 accs = {0,0,0,0};

    for (int jt=0; jt<24; ++jt){
        __syncthreads();   // bar1: ztile[jt] + SFl[jt] ready; prev phase-2 reads done
        if (jt+1 < 24) STAGE(jt+1, (jt+1)&1);

        if (wave < 6){
            const char* zb = (const char*)zbase + (size_t)(jt&1)*16384 + (size_t)jl*512;
            int swz = jl << 4;
            float accA = 0.f, accB = 0.f;
            #pragma unroll
            for (int cc4=0; cc4<16; ++cc4){
                float4 zv = *(const float4*)(zb + ((((chalf<<8) + cc4*16)) ^ swz));
                unsigned uA0 = wbA[cc4*2],   uB0 = wbB[cc4*2];
                unsigned uA1 = wbA[cc4*2+1], uB1 = wbB[cc4*2+1];
                accA = fmaf(zv.x, bf_lo(uA0), accA);
                accA = fmaf(zv.y, bf_hi(uA0), accA);
                accA = fmaf(zv.z, bf_lo(uA1), accA);
                accA = fmaf(zv.w, bf_hi(uA1), accA);
                accB = fmaf(zv.x, bf_lo(uB0), accB);
                accB = fmaf(zv.y, bf_hi(uB0), accB);
                accB = fmaf(zv.z, bf_lo(uB1), accB);
                accB = fmaf(zv.w, bf_hi(uB1), accB);
            }
            accA += __shfl_xor(accA, 32);
            accB += __shfl_xor(accB, 32);
            float LA = accA + SFl[jt&1][h0  ][jl];
            float LB = accB + SFl[jt&1][h0+1][jl];
            float tA = LA, tB = LB;
            #pragma unroll
            for (int off=16; off; off>>=1){
                tA = fmaxf(tA, __shfl_xor(tA, off));
                tB = fmaxf(tB, __shfl_xor(tB, off));
            }
            float mA = fmaxf(m_runA, tA), mB = fmaxf(m_runB, tB);
            float scA = __expf(m_runA - mA), scB = __expf(m_runB - mB);
            float wA = __expf(LA - mA), wB = __expf(LB - mB);
            float sumA = wA, sumB = wB;
            #pragma unroll
            for (int off=16; off; off>>=1){
                sumA += __shfl_xor(sumA, off);
                sumB += __shfl_xor(sumB, off);
            }
            s_runA = fmaf(s_runA, scA, sumA);
            s_runB = fmaf(s_runB, scB, sumB);
            m_runA = mA; m_runB = mB;
            if (chalf == 0) w_l[h0][jl] = wA;
            else            w_l[h0+1][jl] = wB;
            if (lane == 0)  scale_l[h0] = scA;
            if (lane == 32) scale_l[h0+1] = scB;
        } else if (jt+1 < 24){
            int jg = (jt+1)*32 + rS;
            const float4* kp  = (const float4*)(k  + (size_t)jg*192);
            const float4* gkp = (const float4*)(gk + (size_t)jg*144);
            #pragma unroll
            for (int hs=0; hs<3; ++hs){
                int hq = gS*3 + hs;
                float sng = dot4f(qv4[hq*4+0], kp[hq*4+0]) + dot4f(qv4[hq*4+1], kp[hq*4+1])
                          + dot4f(qv4[hq*4+2], kp[hq*4+2]) + dot4f(qv4[hq*4+3], kp[hq*4+3]);
                float fdot = dot4f(gq4[hq*3+0], gkp[hq*3+0]) + dot4f(gq4[hq*3+1], gkp[hq*3+1])
                           + dot4f(gq4[hq*3+2], gkp[hq*3+2]);
                float d2 = qloc[336+hq] + sqk[(size_t)jg*HD + hq] - 2.0f*fdot;
                SFl[(jt+1)&1][hq][rS] = fmaf(SCALE_SINGLE, sng, qloc[348+hq]*d2);
            }
        }
        __syncthreads();   // bar2: w_l/scale_l published; STAGE(jt+1) drained

        if (wave < 6){
            float sclA = scale_l[h0], sclB = scale_l[h0+1];
            azA.x *= sclA; azA.y *= sclA; azA.z *= sclA; azA.w *= sclA;
            azB.x *= sclB; azB.y *= sclB; azB.z *= sclB; azB.w *= sclB;
            const float4* wrA = (const float4*)&w_l[h0  ][chalf<<4];
            const float4* wrB = (const float4*)&w_l[h0+1][chalf<<4];
            float4 wA4[4], wB4[4];
            #pragma unroll
            for (int m=0;m<4;m++){ wA4[m]=wrA[m]; wB4[m]=wrB[m]; }
            const char* zb2 = (const char*)zbase + (size_t)(jt&1)*16384;
            int c4b = jl << 4;
            #pragma unroll
            for (int jj=0; jj<16; ++jj){
                int j = (chalf<<4) + jj;
                float4 zv = *(const float4*)(zb2 + (size_t)j*512 + (c4b ^ (j<<4)));
                float wa  = ((const float*)wA4)[jj];
                float wb2 = ((const float*)wB4)[jj];
                azA.x = fmaf(wa, zv.x, azA.x);
                azA.y = fmaf(wa, zv.y, azA.y);
                azA.z = fmaf(wa, zv.z, azA.z);
                azA.w = fmaf(wa, zv.w, azA.w);
                azB.x = fmaf(wb2, zv.x, azB.x);
                azB.y = fmaf(wb2, zv.y, azB.y);
                azB.z = fmaf(wb2, zv.z, azB.z);
                azB.w = fmaf(wb2, zv.w, azB.w);
            }
        } else if (t >= 384 && t < 504){
            float scl = scale_l[hso];
            accs.x *= scl; accs.y *= scl; accs.z *= scl; accs.w *= scl;
            const float* wrow = &w_l[hso][0];
            #pragma unroll
            for (int jj=0; jj<32; ++jj){
                float w = wrow[jj];
                float4 sv = gsrc[(size_t)(jt*32 + jj)*gstride];
                accs.x = fmaf(w, sv.x, accs.x);
                accs.y = fmaf(w, sv.y, accs.y);
                accs.z = fmaf(w, sv.z, accs.z);
                accs.w = fmaf(w, sv.w, accs.w);
            }
        }
    }

    // combine j-halves; publish denominators
    if (wave < 6){
        azA.x += __shfl_xor(azA.x, 32); azA.y += __shfl_xor(azA.y, 32);
        azA.z += __shfl_xor(azA.z, 32); azA.w += __shfl_xor(azA.w, 32);
        azB.x += __shfl_xor(azB.x, 32); azB.y += __shfl_xor(azB.y, 32);
        azB.z += __shfl_xor(azB.z, 32); azB.w += __shfl_xor(azB.w, 32);
        if (lane == 0)  s_l[h0] = s_runA;
        if (lane == 32) s_l[h0+1] = s_runB;
    }
    __syncthreads();

    if (wave < 6){
        if (chalf == 0){
            float invA = 1.0f / s_runA;
            float invB = 1.0f / s_runB;
            float4 oA = {azA.x*invA, azA.y*invA, azA.z*invA, azA.w*invA};
            float4 oB = {azB.x*invB, azB.y*invB, azB.z*invB, azB.w*invB};
            *(float4*)(att + (size_t)i*DOUT + 192 + (h0  )*128 + jl*4) = oA;
            *(float4*)(att + (size_t)i*DOUT + 192 + (h0+1)*128 + jl*4) = oB;
        }
    } else if (t >= 384 && t < 432){
        float inv = 1.0f / s_l[hso];
        accs.x *= inv; accs.y *= inv; accs.z *= inv; accs.w *= inv;
        int u = t-384;
        ((float4*)(att + (size_t)i*DOUT))[u] = accs;
    } else if (t >= 432 && t < 504){
        float inv = 1.0f / s_l[hso];
        accs.x *= inv; accs.y *= inv; accs.z *= inv; accs.w *= inv;
        int u = t-432;
        ((float4*)so_l)[u] = accs;
    }
    __syncthreads();
    if (t < 96){
        int hq = t >> 3, p = t & 7;
        float d0 = so_l[hq*24+p*3+0] - tv[(size_t)i*3+0];
        float d1 = so_l[hq*24+p*3+1] - tv[(size_t)i*3+1];
        float d2 = so_l[hq*24+p*3+2] - tv[(size_t)i*3+2];
        const float* Ri = R + (size_t)i*9;
        float l0 = fmaf(Ri[0],d0, fmaf(Ri[3],d1, Ri[6]*d2));
        float l1 = fmaf(Ri[1],d0, fmaf(Ri[4],d1, Ri[7]*d2));
        float l2 = fmaf(Ri[2],d0, fmaf(Ri[5],d1, Ri[8]*d2));
        size_t base = (size_t)i*DOUT;
        att[base + 1728 + p*36 + hq*3 + 0] = l0;
        att[base + 1728 + p*36 + hq*3 + 1] = l1;
        att[base + 1728 + p*36 + hq*3 + 2] = l2;
        att[base + 2016 + p*12 + hq] = sqrtf(l0*l0 + l1*l1 + l2*l2);
    }
#undef STAGE
}

// ---------------- K4: final projection att @ Wout + bout ----------------
#define ROWS4 2
__global__ __launch_bounds__(384) void k_final(
    const float* __restrict__ att, const float* __restrict__ Wout, const float* __restrict__ bout,
    float* __restrict__ out)
{
    __shared__ float att_l[ROWS4*DOUT];
    int ib = blockIdx.x * ROWS4, t = threadIdx.x;
    for (int idx=t; idx<ROWS4*DOUT; idx+=384){
        att_l[idx] = att[(size_t)ib*DOUT + idx];
    }
    __syncthreads();
    float a0=0.f,a1=0.f,a2=0.f,a3=0.f;
    float b0=0.f,b1=0.f,b2=0.f,b3=0.f;
    #pragma unroll 4
    for (int d=0; d<DOUT; d+=4){
        float w0 = Wout[(size_t)(d+0)*CSD + t];
        float w1 = Wout[(size_t)(d+1)*CSD + t];
        float w2 = Wout[(size_t)(d+2)*CSD + t];
        float w3 = Wout[(size_t)(d+3)*CSD + t];
        a0 = fmaf(att_l[d+0], w0, a0);
        a1 = fmaf(att_l[d+1], w1, a1);
        a2 = fmaf(att_l[d+2], w2, a2);
        a3 = fmaf(att_l[d+3], w3, a3);
        b0 = fmaf(att_l[DOUT+d+0], w0, b0);
        b1 = fmaf(att_l[DOUT+d+1], w1, b1);
        b2 = fmaf(att_l[DOUT+d+2], w2, b2);
        b3 = fmaf(att_l[DOUT+d+3], w3, b3);
    }
    float bb = bout[t];
    out[(size_t)ib*CSD + t]     = bb + ((a0+a1)+(a2+a3));
    out[(size_t)(ib+1)*CSD + t] = bb + ((b0+b1)+(b2+b3));
}

extern "C" void kernel_launch(void* const* d_in, const int* in_sizes, int n_in,
                              void* d_out, int out_size, void* d_ws, size_t ws_size,
                              hipStream_t stream)
{
    const float* s   = (const float*)d_in[0];
    const float* z   = (const float*)d_in[1];
    const float* R   = (const float*)d_in[2];
    const float* tv  = (const float*)d_in[3];
    const float* Wq  = (const float*)d_in[4];
    const float* Wk  = (const float*)d_in[5];
    const float* Wv  = (const float*)d_in[6];
    const float* Wqp = (const float*)d_in[7];
    const float* Wkp = (const float*)d_in[8];
    const float* Wvp = (const float*)d_in[9];
    const float* Wb  = (const float*)d_in[10];
    const float* Wout= (const float*)d_in[11];
    const float* bout= (const float*)d_in[12];
    const float* sh  = (const float*)d_in[13];

    float* ws  = (float*)d_ws;
    float* q_  = ws;                 // 768*192
    float* k_  = q_  + 147456;       // 768*192
    float* v_  = k_  + 147456;       // 768*192
    float* gq_ = v_  + 147456;       // 768*144
    float* gk_ = gq_ + 110592;       // 768*144
    float* gv_ = gk_ + 110592;       // 768*288
    float* sqq_= gv_ + 221184;       // 768*12
    float* sqk_= sqq_ + 9216;        // 768*12
    float* att_= sqk_ + 9216;        // 768*2112
    float* out = (float*)d_out;

    hipLaunchKernelGGL(k_proj,  dim3(NN/II), dim3(384), 0, stream,
                       s,R,tv,Wq,Wk,Wv,Wqp,Wkp,Wvp, q_,k_,v_,gq_,gk_,gv_,sqq_,sqk_);
    hipLaunchKernelGGL(k_ipa,   dim3(NN),    dim3(512), 0, stream,
                       z,Wb,sh,q_,k_,gq_,gk_,sqq_,sqk_, v_,gv_,R,tv, att_);
    hipLaunchKernelGGL(k_final, dim3(NN/ROWS4), dim3(384), 0, stream,
                       att_,Wout,bout, out);
}

// Round 12
// 435.698 us; speedup vs baseline: 6.0994x; 6.0994x over previous
//
#include <hip/hip_runtime.h>
#include <hip/hip_bf16.h>

#define NN 768
#define CSD 384
#define CZD 128
#define HD 12
#define DOUT 2112
#define II 2

#define SCALE_SINGLE 0.25f
#define SCALE_FRAME (-0.11785113019775793f)   /* -1/sqrt(72) */

__device__ __forceinline__ float dot4f(float4 a, float4 b){
    return fmaf(a.x,b.x, fmaf(a.y,b.y, fmaf(a.z,b.z, a.w*b.w)));
}

// ---------------- K1: projections + frame apply, II=2 residues per block ----------------
__global__ __launch_bounds__(384) void k_proj(
    const float* __restrict__ s, const float* __restrict__ R, const float* __restrict__ tv,
    const float* __restrict__ Wq, const float* __restrict__ Wk, const float* __restrict__ Wv,
    const float* __restrict__ Wqp, const float* __restrict__ Wkp, const float* __restrict__ Wvp,
    float* __restrict__ q, float* __restrict__ k, float* __restrict__ v,
    float* __restrict__ gq, float* __restrict__ gk, float* __restrict__ gv,
    float* __restrict__ sqq, float* __restrict__ sqk)
{
    __shared__ float s_l[II*CSD];
    __shared__ float praw[II][576];
    __shared__ float sq_pt[II][96];
    int i0 = blockIdx.x * II, t = threadIdx.x;
    if (t < II*CSD/4){
        const float4* s4 = (const float4*)(s + (size_t)i0*CSD);
        ((float4*)s_l)[t] = s4[t];
    }
    __syncthreads();

    int cols[3] = {t, t+384, t+768};
    const float* Wp[3]; int st[3], lc[3];
    #pragma unroll
    for (int m=0;m<3;m++){
        int c = cols[m];
        if (c < 192){ Wp[m]=Wq;  st[m]=192; lc[m]=c; }
        else if (c < 384){ Wp[m]=Wk;  st[m]=192; lc[m]=c-192; }
        else if (c < 576){ Wp[m]=Wv;  st[m]=192; lc[m]=c-384; }
        else if (c < 720){ Wp[m]=Wqp; st[m]=144; lc[m]=c-576; }
        else if (c < 864){ Wp[m]=Wkp; st[m]=144; lc[m]=c-720; }
        else { Wp[m]=Wvp; st[m]=288; lc[m]=c-864; }
    }
    float acc[3][II];
    #pragma unroll
    for (int m=0;m<3;m++)
        #pragma unroll
        for (int ii=0;ii<II;ii++) acc[m][ii]=0.f;

    #pragma unroll 4
    for (int r=0;r<CSD;r++){
        float w0 = Wp[0][(size_t)r*st[0]+lc[0]];
        float w1 = Wp[1][(size_t)r*st[1]+lc[1]];
        float w2 = Wp[2][(size_t)r*st[2]+lc[2]];
        #pragma unroll
        for (int ii=0;ii<II;ii++){
            float sv = s_l[ii*CSD + r];
            acc[0][ii] = fmaf(sv, w0, acc[0][ii]);
            acc[1][ii] = fmaf(sv, w1, acc[1][ii]);
            acc[2][ii] = fmaf(sv, w2, acc[2][ii]);
        }
    }
    #pragma unroll
    for (int m=0;m<3;m++){
        int c = cols[m];
        #pragma unroll
        for (int ii=0;ii<II;ii++){
            float val = acc[m][ii];
            size_t i = i0 + ii;
            if (c < 192) q[i*192 + c] = val;
            else if (c < 384) k[i*192 + (c-192)] = val;
            else if (c < 576) v[i*192 + (c-384)] = val;
            else praw[ii][c-576] = val;
        }
    }
    __syncthreads();

    if (t < 192){
        #pragma unroll
        for (int ii=0;ii<II;ii++){
            size_t i = i0 + ii;
            const float* Ri = R + i*9;
            float R00=Ri[0],R01=Ri[1],R02=Ri[2];
            float R10=Ri[3],R11=Ri[4],R12=Ri[5];
            float R20=Ri[6],R21=Ri[7],R22=Ri[8];
            float t0=tv[i*3+0],t1=tv[i*3+1],t2=tv[i*3+2];
            int src; float* dst; int sqslot=-1;
            if (t < 48){ src = t*3; dst = gq + i*144 + t*3; sqslot = t; }
            else if (t < 96){ int u=t-48; src = 144+u*3; dst = gk + i*144 + u*3; sqslot = 48+u; }
            else { int u=t-96; src = 288+u*3; dst = gv + i*288 + u*3; }
            float x=praw[ii][src], y=praw[ii][src+1], zc=praw[ii][src+2];
            float g0 = fmaf(R00,x, fmaf(R01,y, fmaf(R02,zc, t0)));
            float g1 = fmaf(R10,x, fmaf(R11,y, fmaf(R12,zc, t1)));
            float g2 = fmaf(R20,x, fmaf(R21,y, fmaf(R22,zc, t2)));
            dst[0]=g0; dst[1]=g1; dst[2]=g2;
            if (sqslot >= 0) sq_pt[ii][sqslot] = g0*g0 + g1*g1 + g2*g2;
        }
    }
    __syncthreads();
    if (t < II*HD){
        int ii = t / HD, h = t % HD;
        float s1 = sq_pt[ii][h*4]+sq_pt[ii][h*4+1]+sq_pt[ii][h*4+2]+sq_pt[ii][h*4+3];
        float s2 = sq_pt[ii][48+h*4]+sq_pt[ii][48+h*4+1]+sq_pt[ii][48+h*4+2]+sq_pt[ii][48+h*4+3];
        sqq[(size_t)(i0+ii)*HD + h] = s1;
        sqk[(size_t)(i0+ii)*HD + h] = s2;
    }
}

// ---------------- K2: fused logits + softmax + outputs (R5's 313-us kernel, verbatim) ----------------
// block = one i, 512 threads = 8 waves.
// Phase A: stream z[i] (64-row swizzled LDS tiles); waves 0-3 pair term, waves 4-7
//          single+frame; exchange; softmax -> a_l in LDS.
// Phase B: re-stream z[i] (L2/L3-warm, 32-row tiles); o_z (384 thr), o_s (48), so (72);
//          inverse frame epilogue.
__global__ __launch_bounds__(512) void k_ipa(
    const float* __restrict__ z, const float* __restrict__ Wb, const float* __restrict__ scale_head,
    const float* __restrict__ q, const float* __restrict__ k,
    const float* __restrict__ gq, const float* __restrict__ gk,
    const float* __restrict__ sqq, const float* __restrict__ sqk,
    const float* __restrict__ v, const float* __restrict__ gv,
    const float* __restrict__ R, const float* __restrict__ tv,
    float* __restrict__ att)
{
    __shared__ float ztile[2][64][CZD];   // 64KB: phase-A dbuf; reused as exchange + phase-B dbuf
    __shared__ float wbT[HD*CZD];         // [h][c]
    __shared__ float qloc[360];           // q(192) gq(144) sqq(12) sp(12)
    __shared__ float a_l[HD][NN];         // softmax'd attention, block-local
    __shared__ float so_l[288];

    int i = blockIdx.x, t = threadIdx.x;
    int wave = t >> 6, lane = t & 63;

    for (int idx=t; idx<HD*CZD; idx+=512){
        int h = idx >> 7, c = idx & 127;
        wbT[idx] = Wb[(size_t)c*HD + h];
    }
    if (t < 192) qloc[t] = q[(size_t)i*192 + t];
    else if (t < 336) qloc[t] = gq[(size_t)i*144 + (t-192)];
    else if (t < 348) qloc[t] = sqq[(size_t)i*HD + (t-336)];
    else if (t < 360){
        int h = t-348;
        float shv = scale_head[h];
        float sp = (shv > 20.f) ? shv : log1pf(__expf(shv));
        qloc[t] = SCALE_FRAME * sp;
    }

    const char* zi = (const char*)(z + (size_t)i*NN*CZD);
    float* zbase = &ztile[0][0][0];

    // phase A: 64-row tile (32KB), linear LDS dest, inverse-swizzled global src; all 512 threads
#define STAGEL(JT, BUF) do { \
    const char* _zb = zi + (size_t)(JT)*32768; \
    char* _lb = (char*)zbase + (size_t)(BUF)*32768; \
    _Pragma("unroll") \
    for (int _m=0;_m<4;_m++){ \
        int _d = t*16 + _m*8192; \
        int _j = _d >> 9; \
        int _b = _d & 511; \
        int _sb = _b ^ ((_j & 31) << 4); \
        __builtin_amdgcn_global_load_lds((const __attribute__((address_space(1))) void*)(_zb + (size_t)_j*512 + _sb), \
            (__attribute__((address_space(3))) void*)(_lb + _d), 16, 0, 0); \
    } \
  } while(0)

    // phase B: 32-row tile (16KB), linear, all 512 threads (2 x 16B each)
#define STAGEB(JT, BUF) do { \
    const float* _s = (const float*)zi + (size_t)(JT)*4096 + t*4; \
    float* _d = zbase + (size_t)(BUF)*4096 + t*4; \
    __builtin_amdgcn_global_load_lds((const __attribute__((address_space(1))) void*)_s, \
        (__attribute__((address_space(3))) void*)_d, 16, 0, 0); \
    __builtin_amdgcn_global_load_lds((const __attribute__((address_space(1))) void*)(_s+2048), \
        (__attribute__((address_space(3))) void*)(_d+2048), 16, 0, 0); \
  } while(0)

    STAGEL(0, 0);

    int hg = (wave < 4) ? wave : (wave - 4);
    int h0 = hg * 3;
    float L[12][3];

    __syncthreads();   // wbT/qloc visible; STAGEL(0) drained

    {
        const float4* wb4 = (const float4*)wbT;
        const float4* qv4 = (const float4*)qloc;
        const float4* gq4 = (const float4*)(qloc + 192);
        int xoff = (lane & 31) << 4;

        for (int jt=0; jt<12; ++jt){
            int cur = jt & 1;
            if (jt+1 < 12) STAGEL(jt+1, cur^1);
            if (wave < 4){
                const char* zb = (const char*)(zbase + (size_t)cur*8192) + lane*512;
                float p0=0.f, p1=0.f, p2=0.f;
                #pragma unroll 8
                for (int c4=0; c4<32; ++c4){
                    float4 zv = *(const float4*)(zb + ((c4*16) ^ xoff));
                    p0 += dot4f(zv, wb4[(h0+0)*32 + c4]);
                    p1 += dot4f(zv, wb4[(h0+1)*32 + c4]);
                    p2 += dot4f(zv, wb4[(h0+2)*32 + c4]);
                }
                L[jt][0]=p0; L[jt][1]=p1; L[jt][2]=p2;
            } else {
                int jg = jt*64 + lane;
                const float4* kp  = (const float4*)(k  + (size_t)jg*192);
                const float4* gkp = (const float4*)(gk + (size_t)jg*144);
                #pragma unroll
                for (int hs=0; hs<3; ++hs){
                    int h = h0 + hs;
                    float sng = dot4f(qv4[h*4+0], kp[h*4+0]) + dot4f(qv4[h*4+1], kp[h*4+1])
                              + dot4f(qv4[h*4+2], kp[h*4+2]) + dot4f(qv4[h*4+3], kp[h*4+3]);
                    float fdot = dot4f(gq4[h*3+0], gkp[h*3+0]) + dot4f(gq4[h*3+1], gkp[h*3+1])
                               + dot4f(gq4[h*3+2], gkp[h*3+2]);
                    float d2 = qloc[336+h] + sqk[(size_t)jg*HD + h] - 2.0f*fdot;
                    L[jt][hs] = fmaf(SCALE_SINGLE, sng, qloc[348+h]*d2);
                }
            }
            __syncthreads();
        }
    }

    // exchange: single/frame waves deposit; pair waves add + softmax -> a_l
    float* S_l = zbase;
    if (wave >= 4){
        int base = (hg*64 + lane) * 37;
        #pragma unroll
        for (int jt=0; jt<12; ++jt)
            #pragma unroll
            for (int hs=0; hs<3; ++hs)
                S_l[base + jt*3 + hs] = L[jt][hs];
    }
    __syncthreads();
    if (wave < 4){
        int base = (hg*64 + lane) * 37;
        #pragma unroll
        for (int jt=0; jt<12; ++jt)
            #pragma unroll
            for (int hs=0; hs<3; ++hs)
                L[jt][hs] += S_l[base + jt*3 + hs];

        #pragma unroll
        for (int hs=0; hs<3; ++hs){
            float m = -1e30f;
            #pragma unroll
            for (int jt=0; jt<12; ++jt) m = fmaxf(m, L[jt][hs]);
            #pragma unroll
            for (int off=32; off; off>>=1) m = fmaxf(m, __shfl_xor(m, off));
            float ssum = 0.f;
            #pragma unroll
            for (int jt=0; jt<12; ++jt){ float e = __expf(L[jt][hs]-m); L[jt][hs]=e; ssum += e; }
            #pragma unroll
            for (int off=32; off; off>>=1) ssum += __shfl_xor(ssum, off);
            float inv = 1.0f/ssum;
            #pragma unroll
            for (int jt=0; jt<12; ++jt){
                a_l[h0+hs][jt*64 + lane] = L[jt][hs]*inv;
            }
        }
    }
    __syncthreads();   // a_l complete; exchange region free for phase B

    // ---------------- phase B ----------------
    STAGEB(0, 0);

    int hs = 0;
    const float4* gsrc = nullptr;
    int gstride = 0;
    if (t < 384){ hs = t>>5; }
    else if (t < 432){ int u=t-384; hs = u>>2; gsrc = (const float4*)v  + hs*4 + (u&3); gstride = 48; }
    else if (t < 504){ int u=t-432; hs = u/6;  gsrc = (const float4*)gv + hs*6 + (u%6); gstride = 72; }
    float4 acc = {0.f,0.f,0.f,0.f};
    int c4 = t & 31;

    __syncthreads();   // STAGEB(0) drained

    for (int jt=0; jt<24; ++jt){
        int cur = jt & 1;
        if (jt+1 < 24) STAGEB(jt+1, cur^1);
        if (t < 384){
            const float4* arow4 = (const float4*)&a_l[hs][0];
            float4 af[8];
            #pragma unroll
            for (int m=0;m<8;m++) af[m] = arow4[jt*8 + m];
            const float4* zt4 = (const float4*)(zbase + (size_t)cur*4096);
            #pragma unroll
            for (int jj=0;jj<32;jj++){
                float aw = ((const float*)af)[jj];
                float4 zv = zt4[jj*32 + c4];
                acc.x = fmaf(aw, zv.x, acc.x);
                acc.y = fmaf(aw, zv.y, acc.y);
                acc.z = fmaf(aw, zv.z, acc.z);
                acc.w = fmaf(aw, zv.w, acc.w);
            }
        } else if (t < 504){
            const float* arow = &a_l[hs][0];
            #pragma unroll
            for (int jj=0;jj<32;jj++){
                int j = jt*32 + jj;
                float aw = arow[j];
                float4 sv = gsrc[(size_t)j*gstride];
                acc.x = fmaf(aw, sv.x, acc.x);
                acc.y = fmaf(aw, sv.y, acc.y);
                acc.z = fmaf(aw, sv.z, acc.z);
                acc.w = fmaf(aw, sv.w, acc.w);
            }
        }
        __syncthreads();
    }

    if (t < 384){
        float4* dst = (float4*)(att + (size_t)i*DOUT + 192) + (hs*32 + c4);
        *dst = acc;
    } else if (t < 432){
        int u = t-384;
        float4* dst = (float4*)(att + (size_t)i*DOUT) + u;
        *dst = acc;
    } else if (t < 504){
        int u = t-432;
        ((float4*)so_l)[u] = acc;
    }
    __syncthreads();
    if (t < 96){
        int h = t >> 3, p = t & 7;
        float d0 = so_l[h*24+p*3+0] - tv[(size_t)i*3+0];
        float d1 = so_l[h*24+p*3+1] - tv[(size_t)i*3+1];
        float d2 = so_l[h*24+p*3+2] - tv[(size_t)i*3+2];
        const float* Ri = R + (size_t)i*9;
        float l0 = fmaf(Ri[0],d0, fmaf(Ri[3],d1, Ri[6]*d2));
        float l1 = fmaf(Ri[1],d0, fmaf(Ri[4],d1, Ri[7]*d2));
        float l2 = fmaf(Ri[2],d0, fmaf(Ri[5],d1, Ri[8]*d2));
        size_t base = (size_t)i*DOUT;
        att[base + 1728 + p*36 + h*3 + 0] = l0;
        att[base + 1728 + p*36 + h*3 + 1] = l1;
        att[base + 1728 + p*36 + h*3 + 2] = l2;
        att[base + 2016 + p*12 + h] = sqrtf(l0*l0 + l1*l1 + l2*l2);
    }
#undef STAGEL
#undef STAGEB
}

// ---------------- K4: final projection att @ Wout + bout ----------------
#define ROWS4 2
__global__ __launch_bounds__(384) void k_final(
    const float* __restrict__ att, const float* __restrict__ Wout, const float* __restrict__ bout,
    float* __restrict__ out)
{
    __shared__ float att_l[ROWS4*DOUT];
    int ib = blockIdx.x * ROWS4, t = threadIdx.x;
    for (int idx=t; idx<ROWS4*DOUT; idx+=384){
        att_l[idx] = att[(size_t)ib*DOUT + idx];
    }
    __syncthreads();
    float a0=0.f,a1=0.f,a2=0.f,a3=0.f;
    float b0=0.f,b1=0.f,b2=0.f,b3=0.f;
    #pragma unroll 4
    for (int d=0; d<DOUT; d+=4){
        float w0 = Wout[(size_t)(d+0)*CSD + t];
        float w1 = Wout[(size_t)(d+1)*CSD + t];
        float w2 = Wout[(size_t)(d+2)*CSD + t];
        float w3 = Wout[(size_t)(d+3)*CSD + t];
        a0 = fmaf(att_l[d+0], w0, a0);
        a1 = fmaf(att_l[d+1], w1, a1);
        a2 = fmaf(att_l[d+2], w2, a2);
        a3 = fmaf(att_l[d+3], w3, a3);
        b0 = fmaf(att_l[DOUT+d+0], w0, b0);
        b1 = fmaf(att_l[DOUT+d+1], w1, b1);
        b2 = fmaf(att_l[DOUT+d+2], w2, b2);
        b3 = fmaf(att_l[DOUT+d+3], w3, b3);
    }
    float bb = bout[t];
    out[(size_t)ib*CSD + t]     = bb + ((a0+a1)+(a2+a3));
    out[(size_t)(ib+1)*CSD + t] = bb + ((b0+b1)+(b2+b3));
}

extern "C" void kernel_launch(void* const* d_in, const int* in_sizes, int n_in,
                              void* d_out, int out_size, void* d_ws, size_t ws_size,
                              hipStream_t stream)
{
    const float* s   = (const float*)d_in[0];
    const float* z   = (const float*)d_in[1];
    const float* R   = (const float*)d_in[2];
    const float* tv  = (const float*)d_in[3];
    const float* Wq  = (const float*)d_in[4];
    const float* Wk  = (const float*)d_in[5];
    const float* Wv  = (const float*)d_in[6];
    const float* Wqp = (const float*)d_in[7];
    const float* Wkp = (const float*)d_in[8];
    const float* Wvp = (const float*)d_in[9];
    const float* Wb  = (const float*)d_in[10];
    const float* Wout= (const float*)d_in[11];
    const float* bout= (const float*)d_in[12];
    const float* sh  = (const float*)d_in[13];

    float* ws  = (float*)d_ws;
    float* q_  = ws;                 // 768*192
    float* k_  = q_  + 147456;       // 768*192
    float* v_  = k_  + 147456;       // 768*192
    float* gq_ = v_  + 147456;       // 768*144
    float* gk_ = gq_ + 110592;       // 768*144
    float* gv_ = gk_ + 110592;       // 768*288
    float* sqq_= gv_ + 221184;       // 768*12
    float* sqk_= sqq_ + 9216;        // 768*12
    float* att_= sqk_ + 9216;        // 768*2112
    float* out = (float*)d_out;

    hipLaunchKernelGGL(k_proj,  dim3(NN/II), dim3(384), 0, stream,
                       s,R,tv,Wq,Wk,Wv,Wqp,Wkp,Wvp, q_,k_,v_,gq_,gk_,gv_,sqq_,sqk_);
    hipLaunchKernelGGL(k_ipa,   dim3(NN),    dim3(512), 0, stream,
                       z,Wb,sh,q_,k_,gq_,gk_,sqq_,sqk_, v_,gv_,R,tv, att_);
    hipLaunchKernelGGL(k_final, dim3(NN/ROWS4), dim3(384), 0, stream,
                       att_,Wout,bout, out);
}